// Round 18
// baseline (201.886 us; speedup 1.0000x reference)
//
#include <hip/hip_runtime.h>

#define D 64

static __host__ __device__ inline int alignup(int x) { return (x + 63) & ~63; }

__device__ inline float blo(unsigned int u) { return __uint_as_float(u << 16); }
__device__ inline float bhi(unsigned int u) { return __uint_as_float(u & 0xffff0000u); }
__device__ inline unsigned short f2b(float f) {
    unsigned int u = __float_as_uint(f);
    return (unsigned short)((u + 0x7FFFu + ((u >> 16) & 1u)) >> 16);
}
__device__ inline unsigned int packb(float lo, float hi) {
    return (unsigned int)f2b(lo) | ((unsigned int)f2b(hi) << 16);
}

typedef short bf16x8 __attribute__((ext_vector_type(8)));
typedef float f32x4 __attribute__((ext_vector_type(4)));

// merged prep: [0,nbC) convert x->bf16; [nbC,nbC+16) build WbT (+zero done);
// [nbC+16, nbC+16+BA) per-block bucket histogram of row[] (countA).
__global__ void prep(const float* __restrict__ x, unsigned short* __restrict__ xb,
                     const float* __restrict__ W, unsigned short* __restrict__ wbt,
                     const int* __restrict__ row, int* __restrict__ bhist,
                     int* __restrict__ done,
                     long nElem, int nbC, int E, int chunk, int NB) {
    int blk = (int)blockIdx.x;
    if (blk < nbC) {
        long t = (long)blk * blockDim.x + threadIdx.x;
        long i = t * 4;
        if (i + 3 < nElem) {
            float4 v = *(const float4*)(x + i);
            ushort4 o;
            o.x = f2b(v.x); o.y = f2b(v.y); o.z = f2b(v.z); o.w = f2b(v.w);
            *(ushort4*)(xb + i) = o;
        } else {
            for (long k = i; k < nElem; ++k) xb[k] = f2b(x[k]);
        }
        return;
    }
    if (blk < nbC + 16) {
        if (blk == nbC && threadIdx.x == 0) *done = 0;
        int idx = (blk - nbC) * 256 + threadIdx.x;  // 0..4095
        int c = idx >> 6, k = idx & 63;
        wbt[c * 64 + k] = f2b(W[k * 64 + c]);
        return;
    }
    // countA part
    __shared__ int h[512];
    int b = blk - nbC - 16;
    for (int k = threadIdx.x; k < NB; k += blockDim.x) h[k] = 0;
    __syncthreads();
    int s = b * chunk, e = min(s + chunk, E);
    for (int p = s + (int)threadIdx.x; p < e; p += blockDim.x)
        atomicAdd(&h[row[p] >> 8], 1);
    __syncthreads();
    for (int k = threadIdx.x; k < NB; k += blockDim.x)
        bhist[k * 256 + b] = h[k];
}

// fused scanA + scan_boff: per-bucket scan of bhist columns; the LAST block to
// finish (device atomic) scans bucket totals -> boff. 512 threads/block.
__global__ void scanAB(int* __restrict__ bhist, int* __restrict__ bcnt,
                       int* __restrict__ boff, int NB, int* __restrict__ done) {
    __shared__ int s[256];
    __shared__ int sb[512];
    __shared__ int isLast;
    int k = blockIdx.x;
    int t = threadIdx.x;
    int v = 0;
    if (t < 256) {
        v = bhist[k * 256 + t];
        s[t] = v;
    }
    __syncthreads();
    for (int o = 1; o < 256; o <<= 1) {
        int u = 0;
        if (t < 256 && t >= o) u = s[t - o];
        __syncthreads();
        if (t < 256 && t >= o) s[t] += u;
        __syncthreads();
    }
    if (t < 256) bhist[k * 256 + t] = s[t] - v;  // exclusive within bucket
    if (t == 255) atomicExch(&bcnt[k], s[255]);  // device-visible store
    __threadfence();
    __syncthreads();
    if (t == 0) isLast = (atomicAdd(done, 1) == NB - 1);
    __syncthreads();
    if (!isLast) return;
    int v2 = (t < NB) ? atomicAdd(&bcnt[t], 0) : 0;  // coherent read
    sb[t] = v2;
    __syncthreads();
    for (int o = 1; o < 512; o <<= 1) {
        int u = (t >= o) ? sb[t - o] : 0;
        __syncthreads();
        if (t >= o) sb[t] += u;
        __syncthreads();
    }
    if (t < NB) boff[t] = sb[t] - v2;  // exclusive
}

// ebuf entry: .x = (rowloc<<24) | col  (col < 2^24), .y = raw weight bits
__global__ void scatterB(const int* __restrict__ row, const int* __restrict__ col,
                         const float* __restrict__ w, const int* __restrict__ bhist,
                         const int* __restrict__ boff, uint2* __restrict__ ebuf,
                         int E, int chunk, int NB) {
    __shared__ int cur[512];
    int b = blockIdx.x;
    for (int k = threadIdx.x; k < NB; k += blockDim.x)
        cur[k] = boff[k] + bhist[k * 256 + b];
    __syncthreads();
    int s = b * chunk, e = min(s + chunk, E);
    for (int p = s + (int)threadIdx.x; p < e; p += blockDim.x) {
        int r = row[p];
        int bkt = r >> 8;
        int pos = atomicAdd(&cur[bkt], 1);
        ebuf[pos] = make_uint2(((unsigned)(r & 255) << 24) | (unsigned)col[p],
                               __float_as_uint(w[p]));
    }
}

// per bucket STATS ONLY: count + weight-sum (LDS) -> dinv, LDS scan -> off/end
__global__ void bucketC(const uint2* __restrict__ ebuf, const int* __restrict__ boff,
                        const int* __restrict__ bcnt, float* __restrict__ dinv,
                        int* __restrict__ off, int* __restrict__ endp,
                        int n, float fill) {
    __shared__ int cntS[256];
    __shared__ float wsum[256];
    __shared__ int scanS[256];
    int k = blockIdx.x;
    int t = threadIdx.x;
    cntS[t] = 0;
    wsum[t] = 0.f;
    __syncthreads();
    int s = boff[k], e = s + bcnt[k];
    for (int p = s + t; p < e; p += 256) {
        uint2 ent = ebuf[p];
        int rl = (int)(ent.x >> 24);
        atomicAdd(&cntS[rl], 1);
        atomicAdd(&wsum[rl], __uint_as_float(ent.y));
    }
    __syncthreads();
    int r = k * 256 + t;
    int v = cntS[t];
    scanS[t] = v;
    __syncthreads();
    for (int o = 1; o < 256; o <<= 1) {
        int u = (t >= o) ? scanS[t - o] : 0;
        __syncthreads();
        if (t >= o) scanS[t] += u;
        __syncthreads();
    }
    if (r < n) {
        float d = fill + wsum[t];
        dinv[r] = d > 0.0f ? rsqrtf(d) : 0.0f;
        int base = boff[k] + scanS[t] - v;
        off[r] = base;
        endp[r] = base + v;
    }
}

// place WITH normalization: csr[off[r]+pos] = {c, w * dinv[r] * dinv[c]}.
// Replaces bucketC's place pass + normB (saves a full csr read-modify-write).
__global__ void placeN(const uint2* __restrict__ ebuf, const int* __restrict__ boff,
                       const int* __restrict__ bcnt, const float* __restrict__ dinv,
                       const int* __restrict__ off, uint2* __restrict__ csr, int n) {
    __shared__ float dl[256];
    __shared__ int cur[256];
    int k = blockIdx.x;
    int t = threadIdx.x;
    int r = k * 256 + t;
    dl[t] = (r < n) ? dinv[r] : 0.f;
    cur[t] = (r < n) ? off[r] : 0;
    __syncthreads();
    int s = boff[k], e = s + bcnt[k];
    for (int p = s + t; p < e; p += 256) {
        uint2 ent = ebuf[p];
        int rl = (int)(ent.x >> 24);
        unsigned c = ent.x & 0xFFFFFFu;
        int pos = atomicAdd(&cur[rl], 1);
        float wn = __uint_as_float(ent.y) * dl[rl] * dinv[c];
        csr[pos] = make_uint2(c, __float_as_uint(wn));
    }
}

// 8 nodes per wave; 16 CSR entries per iteration, conditional gathers.
__global__ void __launch_bounds__(256)
hop_g8(const unsigned short* __restrict__ xb, const float* __restrict__ dinv,
       const int* __restrict__ off, const int* __restrict__ end,
       const uint2* __restrict__ csr,
       unsigned short* __restrict__ outb, int n) {
    int t = blockIdx.x * blockDim.x + threadIdx.x;
    int wave = t >> 6;
    int lane = t & 63;
    int g = lane >> 3, q = lane & 7;
    int i = wave * 8 + g;
    bool active = i < n;
    int ii = active ? i : n - 1;

    const unsigned int* xw = (const unsigned int*)xb;
    float di = dinv[ii];
    float di2 = di * di;  // self-loop weight (fill=1): dinv^2
    uint4 sv = *(const uint4*)(xw + (long)ii * 32 + q * 4);
    float a0 = blo(sv.x) * di2, a1 = bhi(sv.x) * di2;
    float a2 = blo(sv.y) * di2, a3 = bhi(sv.y) * di2;
    float a4 = blo(sv.z) * di2, a5 = bhi(sv.z) * di2;
    float a6 = blo(sv.w) * di2, a7 = bhi(sv.w) * di2;

    int s = active ? off[ii] : 0;
    int e = active ? end[ii] : 0;

    for (int b = s; b < e; b += 16) {
        int i0 = b + q;     if (i0 >= e) i0 = e - 1;
        int i1 = b + 8 + q; if (i1 >= e) i1 = e - 1;
        uint2 e0 = csr[i0];
        uint2 e1 = csr[i1];
        uint4 v[16];
        float wv[16];
        #pragma unroll
        for (int j = 0; j < 16; ++j) {
            int srcl = g * 8 + (j & 7);
            int cb = __shfl((int)(j < 8 ? e0.x : e1.x), srcl, 64);
            float wj = __uint_as_float(__shfl((int)(j < 8 ? e0.y : e1.y), srcl, 64));
            if (b + j >= e) wj = 0.0f;
            wv[j] = wj;
            v[j] = make_uint4(0u, 0u, 0u, 0u);
            if (wj != 0.0f) v[j] = *(const uint4*)(xw + (long)cb * 32 + q * 4);
        }
        #pragma unroll
        for (int j = 0; j < 16; ++j) {
            float wj = wv[j];
            a0 += blo(v[j].x) * wj; a1 += bhi(v[j].x) * wj;
            a2 += blo(v[j].y) * wj; a3 += bhi(v[j].y) * wj;
            a4 += blo(v[j].z) * wj; a5 += bhi(v[j].z) * wj;
            a6 += blo(v[j].w) * wj; a7 += bhi(v[j].w) * wj;
        }
    }

    if (!active) return;
    uint4 o;
    o.x = packb(a0, a1); o.y = packb(a2, a3);
    o.z = packb(a4, a5); o.w = packb(a6, a7);
    *(uint4*)((unsigned int*)outb + (long)i * 32 + q * 4) = o;
}

// MFMA projection: one wave per 16-row tile (verified C/D layout).
__global__ void __launch_bounds__(256)
proj_mfma(const unsigned short* __restrict__ h2b, const unsigned short* __restrict__ wbt,
          const float* __restrict__ bias, float* __restrict__ out, int n) {
    int lane = threadIdx.x & 63;
    int w = (blockIdx.x * blockDim.x + threadIdx.x) >> 6;
    int nTiles = (n + 15) >> 4;
    if (w >= nTiles) return;
    int r0 = w * 16;
    int rl = lane & 15;
    int half = lane >> 4;  // 0..3

    int ar = r0 + rl; if (ar >= n) ar = n - 1;
    const unsigned short* arow = h2b + (long)ar * 64 + half * 8;
    bf16x8 A0 = __builtin_bit_cast(bf16x8, *(const uint4*)(arow));
    bf16x8 A1 = __builtin_bit_cast(bf16x8, *(const uint4*)(arow + 32));

    #pragma unroll
    for (int t = 0; t < 4; ++t) {
        const unsigned short* bcol = wbt + (long)(t * 16 + rl) * 64 + half * 8;
        bf16x8 B0 = __builtin_bit_cast(bf16x8, *(const uint4*)(bcol));
        bf16x8 B1 = __builtin_bit_cast(bf16x8, *(const uint4*)(bcol + 32));
        float bl = bias[t * 16 + rl];
        f32x4 acc = {bl, bl, bl, bl};
        acc = __builtin_amdgcn_mfma_f32_16x16x32_bf16(A0, B0, acc, 0, 0, 0);
        acc = __builtin_amdgcn_mfma_f32_16x16x32_bf16(A1, B1, acc, 0, 0, 0);
        #pragma unroll
        for (int j = 0; j < 4; ++j) {
            int r = r0 + half * 4 + j;
            if (r < n) out[(long)r * 64 + t * 16 + rl] = acc[j];
        }
    }
}

extern "C" void kernel_launch(void* const* d_in, const int* in_sizes, int n_in,
                              void* d_out, int out_size, void* d_ws, size_t ws_size,
                              hipStream_t stream) {
    const float* x    = (const float*)d_in[0];
    const int*   ei   = (const int*)d_in[1];
    const float* ew   = (const float*)d_in[2];
    const float* W    = (const float*)d_in[3];
    const float* bias = (const float*)d_in[4];

    int n = in_sizes[0] / D;   // 100000
    int E = in_sizes[2];       // 1600000
    const int* row = ei;
    const int* col = ei + E;

    float* out = (float*)d_out;

    const int NB = (n + 255) >> 8;   // 391 buckets
    const int BA = 256;
    int chunk = (E + BA - 1) / BA;

    // workspace layout (4-byte units)
    float* dinv  = (float*)d_ws;                  // n
    int*   off   = (int*)(dinv + alignup(n));     // n
    int*   endp  = off + alignup(n);              // n
    int*   bcnt  = endp + alignup(n);             // 512
    int*   boff  = bcnt + 512;                    // 512
    int*   done  = boff + 512;                    // 1 (+pad)
    int*   bhist = done + 64;                     // NB*256
    uint2* csr   = (uint2*)(bhist + alignup(NB * 256)); // E x 8B
    unsigned short* xb  = (unsigned short*)(csr + alignup(E)); // n*D bf16
    unsigned short* h1b = xb + (long)alignup(n) * D;           // n*D bf16
    unsigned short* h2b = h1b + (long)alignup(n) * D;          // n*D bf16
    unsigned short* wbt = h2b + (long)alignup(n) * D;          // 64*64 bf16
    uint2* ebuf = (uint2*)h2b;  // aliases h2b: consumed before hop2 writes it

    const float fill = 1.0f;  // IMPROVED = False
    const int blk = 256;

    long nElem = (long)n * D;
    int nbC = (int)((nElem / 4 + blk - 1) / blk);
    prep<<<nbC + 16 + BA, blk, 0, stream>>>(x, xb, W, wbt, row, bhist, done,
                                            nElem, nbC, E, chunk, NB);

    scanAB<<<NB, 512, 0, stream>>>(bhist, bcnt, boff, NB, done);
    scatterB<<<BA, 256, 0, stream>>>(row, col, ew, bhist, boff, ebuf, E, chunk, NB);
    bucketC<<<NB, 256, 0, stream>>>(ebuf, boff, bcnt, dinv, off, endp, n, fill);
    placeN<<<NB, 256, 0, stream>>>(ebuf, boff, bcnt, dinv, off, csr, n);

    int nWaves = (n + 7) / 8;
    int nbHop = (nWaves * 64 + blk - 1) / blk;
    hop_g8<<<nbHop, blk, 0, stream>>>(xb, dinv, off, endp, csr, h1b, n);
    hop_g8<<<nbHop, blk, 0, stream>>>(h1b, dinv, off, endp, csr, h2b, n);

    int nTiles = (n + 15) / 16;
    int nbProj = (nTiles * 64 + blk - 1) / blk;
    proj_mfma<<<nbProj, blk, 0, stream>>>(h2b, wbt, bias, out, n);
}

// Round 19
// 155.745 us; speedup vs baseline: 1.2963x; 1.2963x over previous
//
#include <hip/hip_runtime.h>

#define D 64

static __host__ __device__ inline int alignup(int x) { return (x + 63) & ~63; }

__device__ inline float blo(unsigned int u) { return __uint_as_float(u << 16); }
__device__ inline float bhi(unsigned int u) { return __uint_as_float(u & 0xffff0000u); }
__device__ inline unsigned short f2b(float f) {
    unsigned int u = __float_as_uint(f);
    return (unsigned short)((u + 0x7FFFu + ((u >> 16) & 1u)) >> 16);
}
__device__ inline unsigned int packb(float lo, float hi) {
    return (unsigned int)f2b(lo) | ((unsigned int)f2b(hi) << 16);
}

typedef short bf16x8 __attribute__((ext_vector_type(8)));
typedef float f32x4 __attribute__((ext_vector_type(4)));

// merged prep: [0,nbC) convert x->bf16; [nbC,nbC+16) build WbT;
// [nbC+16, nbC+16+BA) per-block bucket histogram of row[] (countA).
__global__ void prep(const float* __restrict__ x, unsigned short* __restrict__ xb,
                     const float* __restrict__ W, unsigned short* __restrict__ wbt,
                     const int* __restrict__ row, int* __restrict__ bhist,
                     long nElem, int nbC, int E, int chunk, int NB) {
    int blk = (int)blockIdx.x;
    if (blk < nbC) {
        long t = (long)blk * blockDim.x + threadIdx.x;
        long i = t * 4;
        if (i + 3 < nElem) {
            float4 v = *(const float4*)(x + i);
            ushort4 o;
            o.x = f2b(v.x); o.y = f2b(v.y); o.z = f2b(v.z); o.w = f2b(v.w);
            *(ushort4*)(xb + i) = o;
        } else {
            for (long k = i; k < nElem; ++k) xb[k] = f2b(x[k]);
        }
        return;
    }
    if (blk < nbC + 16) {
        int idx = (blk - nbC) * 256 + threadIdx.x;  // 0..4095
        int c = idx >> 6, k = idx & 63;
        wbt[c * 64 + k] = f2b(W[k * 64 + c]);
        return;
    }
    // countA part
    __shared__ int h[512];
    int b = blk - nbC - 16;
    for (int k = threadIdx.x; k < NB; k += blockDim.x) h[k] = 0;
    __syncthreads();
    int s = b * chunk, e = min(s + chunk, E);
    for (int p = s + (int)threadIdx.x; p < e; p += blockDim.x)
        atomicAdd(&h[row[p] >> 8], 1);
    __syncthreads();
    for (int k = threadIdx.x; k < NB; k += blockDim.x)
        bhist[k * 256 + b] = h[k];
}

// ---------- bucket-sort CSR build: LDS atomics only, ZERO global atomics ----
__global__ void scanA(int* __restrict__ bhist, int* __restrict__ bcnt, int NB) {
    __shared__ int s[256];
    int k = blockIdx.x;
    int t = threadIdx.x;
    int v = bhist[k * 256 + t];
    s[t] = v;
    __syncthreads();
    for (int o = 1; o < 256; o <<= 1) {
        int u = (t >= o) ? s[t - o] : 0;
        __syncthreads();
        if (t >= o) s[t] += u;
        __syncthreads();
    }
    bhist[k * 256 + t] = s[t] - v;  // exclusive within bucket
    if (t == 255) bcnt[k] = s[t];
}

__global__ void scan_boff(const int* __restrict__ bcnt, int* __restrict__ boff, int nb) {
    __shared__ int s[512];
    int t = threadIdx.x;
    s[t] = (t < nb) ? bcnt[t] : 0;
    __syncthreads();
    for (int o = 1; o < 512; o <<= 1) {
        int v = (t >= o) ? s[t - o] : 0;
        __syncthreads();
        if (t >= o) s[t] += v;
        __syncthreads();
    }
    if (t < nb) boff[t] = (t == 0) ? 0 : s[t - 1];
}

// ebuf entry: .x = (rowloc<<24) | col  (col < 2^24), .y = raw weight bits
__global__ void scatterB(const int* __restrict__ row, const int* __restrict__ col,
                         const float* __restrict__ w, const int* __restrict__ bhist,
                         const int* __restrict__ boff, uint2* __restrict__ ebuf,
                         int E, int chunk, int NB) {
    __shared__ int cur[512];
    int b = blockIdx.x;
    for (int k = threadIdx.x; k < NB; k += blockDim.x)
        cur[k] = boff[k] + bhist[k * 256 + b];
    __syncthreads();
    int s = b * chunk, e = min(s + chunk, E);
    for (int p = s + (int)threadIdx.x; p < e; p += blockDim.x) {
        int r = row[p];
        int bkt = r >> 8;
        int pos = atomicAdd(&cur[bkt], 1);
        ebuf[pos] = make_uint2(((unsigned)(r & 255) << 24) | (unsigned)col[p],
                               __float_as_uint(w[p]));
    }
}

// per bucket STATS ONLY: count + weight-sum (LDS) -> dinv, LDS scan -> off/end
__global__ void bucketC(const uint2* __restrict__ ebuf, const int* __restrict__ boff,
                        const int* __restrict__ bcnt, float* __restrict__ dinv,
                        int* __restrict__ off, int* __restrict__ endp,
                        int n, float fill) {
    __shared__ int cntS[256];
    __shared__ float wsum[256];
    __shared__ int scanS[256];
    int k = blockIdx.x;
    int t = threadIdx.x;
    cntS[t] = 0;
    wsum[t] = 0.f;
    __syncthreads();
    int s = boff[k], e = s + bcnt[k];
    for (int p = s + t; p < e; p += 256) {
        uint2 ent = ebuf[p];
        int rl = (int)(ent.x >> 24);
        atomicAdd(&cntS[rl], 1);
        atomicAdd(&wsum[rl], __uint_as_float(ent.y));
    }
    __syncthreads();
    int r = k * 256 + t;
    int v = cntS[t];
    scanS[t] = v;
    __syncthreads();
    for (int o = 1; o < 256; o <<= 1) {
        int u = (t >= o) ? scanS[t - o] : 0;
        __syncthreads();
        if (t >= o) scanS[t] += u;
        __syncthreads();
    }
    if (r < n) {
        float d = fill + wsum[t];
        dinv[r] = d > 0.0f ? rsqrtf(d) : 0.0f;
        int base = boff[k] + scanS[t] - v;
        off[r] = base;
        endp[r] = base + v;
    }
}

// place WITH normalization: csr[off[r]+pos] = {c, w * dinv[r] * dinv[c]}.
__global__ void placeN(const uint2* __restrict__ ebuf, const int* __restrict__ boff,
                       const int* __restrict__ bcnt, const float* __restrict__ dinv,
                       const int* __restrict__ off, uint2* __restrict__ csr, int n) {
    __shared__ float dl[256];
    __shared__ int cur[256];
    int k = blockIdx.x;
    int t = threadIdx.x;
    int r = k * 256 + t;
    dl[t] = (r < n) ? dinv[r] : 0.f;
    cur[t] = (r < n) ? off[r] : 0;
    __syncthreads();
    int s = boff[k], e = s + bcnt[k];
    for (int p = s + t; p < e; p += 256) {
        uint2 ent = ebuf[p];
        int rl = (int)(ent.x >> 24);
        unsigned c = ent.x & 0xFFFFFFu;
        int pos = atomicAdd(&cur[rl], 1);
        float wn = __uint_as_float(ent.y) * dl[rl] * dinv[c];
        csr[pos] = make_uint2(c, __float_as_uint(wn));
    }
}

// 8 nodes per wave; 16 CSR entries per iteration, conditional gathers.
__global__ void __launch_bounds__(256)
hop_g8(const unsigned short* __restrict__ xb, const float* __restrict__ dinv,
       const int* __restrict__ off, const int* __restrict__ end,
       const uint2* __restrict__ csr,
       unsigned short* __restrict__ outb, int n) {
    int t = blockIdx.x * blockDim.x + threadIdx.x;
    int wave = t >> 6;
    int lane = t & 63;
    int g = lane >> 3, q = lane & 7;
    int i = wave * 8 + g;
    bool active = i < n;
    int ii = active ? i : n - 1;

    const unsigned int* xw = (const unsigned int*)xb;
    float di = dinv[ii];
    float di2 = di * di;  // self-loop weight (fill=1): dinv^2
    uint4 sv = *(const uint4*)(xw + (long)ii * 32 + q * 4);
    float a0 = blo(sv.x) * di2, a1 = bhi(sv.x) * di2;
    float a2 = blo(sv.y) * di2, a3 = bhi(sv.y) * di2;
    float a4 = blo(sv.z) * di2, a5 = bhi(sv.z) * di2;
    float a6 = blo(sv.w) * di2, a7 = bhi(sv.w) * di2;

    int s = active ? off[ii] : 0;
    int e = active ? end[ii] : 0;

    for (int b = s; b < e; b += 16) {
        int i0 = b + q;     if (i0 >= e) i0 = e - 1;
        int i1 = b + 8 + q; if (i1 >= e) i1 = e - 1;
        uint2 e0 = csr[i0];
        uint2 e1 = csr[i1];
        uint4 v[16];
        float wv[16];
        #pragma unroll
        for (int j = 0; j < 16; ++j) {
            int srcl = g * 8 + (j & 7);
            int cb = __shfl((int)(j < 8 ? e0.x : e1.x), srcl, 64);
            float wj = __uint_as_float(__shfl((int)(j < 8 ? e0.y : e1.y), srcl, 64));
            if (b + j >= e) wj = 0.0f;
            wv[j] = wj;
            v[j] = make_uint4(0u, 0u, 0u, 0u);
            if (wj != 0.0f) v[j] = *(const uint4*)(xw + (long)cb * 32 + q * 4);
        }
        #pragma unroll
        for (int j = 0; j < 16; ++j) {
            float wj = wv[j];
            a0 += blo(v[j].x) * wj; a1 += bhi(v[j].x) * wj;
            a2 += blo(v[j].y) * wj; a3 += bhi(v[j].y) * wj;
            a4 += blo(v[j].z) * wj; a5 += bhi(v[j].z) * wj;
            a6 += blo(v[j].w) * wj; a7 += bhi(v[j].w) * wj;
        }
    }

    if (!active) return;
    uint4 o;
    o.x = packb(a0, a1); o.y = packb(a2, a3);
    o.z = packb(a4, a5); o.w = packb(a6, a7);
    *(uint4*)((unsigned int*)outb + (long)i * 32 + q * 4) = o;
}

// MFMA projection: one wave per 16-row tile (verified C/D layout).
__global__ void __launch_bounds__(256)
proj_mfma(const unsigned short* __restrict__ h2b, const unsigned short* __restrict__ wbt,
          const float* __restrict__ bias, float* __restrict__ out, int n) {
    int lane = threadIdx.x & 63;
    int w = (blockIdx.x * blockDim.x + threadIdx.x) >> 6;
    int nTiles = (n + 15) >> 4;
    if (w >= nTiles) return;
    int r0 = w * 16;
    int rl = lane & 15;
    int half = lane >> 4;  // 0..3

    int ar = r0 + rl; if (ar >= n) ar = n - 1;
    const unsigned short* arow = h2b + (long)ar * 64 + half * 8;
    bf16x8 A0 = __builtin_bit_cast(bf16x8, *(const uint4*)(arow));
    bf16x8 A1 = __builtin_bit_cast(bf16x8, *(const uint4*)(arow + 32));

    #pragma unroll
    for (int t = 0; t < 4; ++t) {
        const unsigned short* bcol = wbt + (long)(t * 16 + rl) * 64 + half * 8;
        bf16x8 B0 = __builtin_bit_cast(bf16x8, *(const uint4*)(bcol));
        bf16x8 B1 = __builtin_bit_cast(bf16x8, *(const uint4*)(bcol + 32));
        float bl = bias[t * 16 + rl];
        f32x4 acc = {bl, bl, bl, bl};
        acc = __builtin_amdgcn_mfma_f32_16x16x32_bf16(A0, B0, acc, 0, 0, 0);
        acc = __builtin_amdgcn_mfma_f32_16x16x32_bf16(A1, B1, acc, 0, 0, 0);
        #pragma unroll
        for (int j = 0; j < 4; ++j) {
            int r = r0 + half * 4 + j;
            if (r < n) out[(long)r * 64 + t * 16 + rl] = acc[j];
        }
    }
}

extern "C" void kernel_launch(void* const* d_in, const int* in_sizes, int n_in,
                              void* d_out, int out_size, void* d_ws, size_t ws_size,
                              hipStream_t stream) {
    const float* x    = (const float*)d_in[0];
    const int*   ei   = (const int*)d_in[1];
    const float* ew   = (const float*)d_in[2];
    const float* W    = (const float*)d_in[3];
    const float* bias = (const float*)d_in[4];

    int n = in_sizes[0] / D;   // 100000
    int E = in_sizes[2];       // 1600000
    const int* row = ei;
    const int* col = ei + E;

    float* out = (float*)d_out;

    const int NB = (n + 255) >> 8;   // 391 buckets
    const int BA = 256;
    int chunk = (E + BA - 1) / BA;

    // workspace layout (4-byte units)
    float* dinv  = (float*)d_ws;                  // n
    int*   off   = (int*)(dinv + alignup(n));     // n
    int*   endp  = off + alignup(n);              // n
    int*   bcnt  = endp + alignup(n);             // 512
    int*   boff  = bcnt + 512;                    // 512
    int*   bhist = boff + 512;                    // NB*256
    uint2* csr   = (uint2*)(bhist + alignup(NB * 256)); // E x 8B
    unsigned short* xb  = (unsigned short*)(csr + alignup(E)); // n*D bf16
    unsigned short* h1b = xb + (long)alignup(n) * D;           // n*D bf16
    unsigned short* h2b = h1b + (long)alignup(n) * D;          // n*D bf16
    unsigned short* wbt = h2b + (long)alignup(n) * D;          // 64*64 bf16
    uint2* ebuf = (uint2*)h2b;  // aliases h2b: consumed before hop2 writes it

    const float fill = 1.0f;  // IMPROVED = False
    const int blk = 256;

    long nElem = (long)n * D;
    int nbC = (int)((nElem / 4 + blk - 1) / blk);
    prep<<<nbC + 16 + BA, blk, 0, stream>>>(x, xb, W, wbt, row, bhist,
                                            nElem, nbC, E, chunk, NB);

    scanA<<<NB, 256, 0, stream>>>(bhist, bcnt, NB);
    scan_boff<<<1, 512, 0, stream>>>(bcnt, boff, NB);
    scatterB<<<BA, 256, 0, stream>>>(row, col, ew, bhist, boff, ebuf, E, chunk, NB);
    bucketC<<<NB, 256, 0, stream>>>(ebuf, boff, bcnt, dinv, off, endp, n, fill);
    placeN<<<NB, 256, 0, stream>>>(ebuf, boff, bcnt, dinv, off, csr, n);

    int nWaves = (n + 7) / 8;
    int nbHop = (nWaves * 64 + blk - 1) / blk;
    hop_g8<<<nbHop, blk, 0, stream>>>(xb, dinv, off, endp, csr, h1b, n);
    hop_g8<<<nbHop, blk, 0, stream>>>(h1b, dinv, off, endp, csr, h2b, n);

    int nTiles = (n + 15) / 16;
    int nbProj = (nTiles * 64 + blk - 1) / blk;
    proj_mfma<<<nbProj, blk, 0, stream>>>(h2b, wbt, bias, out, n);
}